// Round 5
// baseline (241.440 us; speedup 1.0000x reference)
//
#include <hip/hip_runtime.h>
#include <hip/hip_bf16.h>

typedef unsigned short u16;
typedef __bf16 bf16x8 __attribute__((ext_vector_type(8)));
typedef float f32x4 __attribute__((ext_vector_type(4)));

#define HIDDEN 1024
#define NH 16
#define HD 64
#define BATCH 2
#define SEQ 2048
#define MTOT (BATCH*SEQ)   // 4096
#define CEXP 0.18033688f   // 0.125 * log2(e), folded into Q

__device__ __forceinline__ u16 f2bf(float f) {
  union { float f; unsigned u; } v; v.f = f;
  unsigned u = v.u;
  return (u16)((u + 0x7fffu + ((u >> 16) & 1u)) >> 16);   // RNE
}

__device__ __forceinline__ unsigned pack2bf(float a, float b) {
  __hip_bfloat162 h = __float22bfloat162_rn(make_float2(a, b));
  unsigned u; __builtin_memcpy(&u, &h, 4); return u;
}

__device__ __forceinline__ void gload16(const u16* g, u16* l) {
  __builtin_amdgcn_global_load_lds((const __attribute__((address_space(1))) unsigned int*)g,
                                   (__attribute__((address_space(3))) unsigned int*)l, 16, 0, 0);
}

// ---------------- prep: x fp32 -> bf16 ----------------
__global__ __launch_bounds__(256) void convert_x_kernel(const float* __restrict__ x,
                                                        u16* __restrict__ xb) {
  size_t i = ((size_t)blockIdx.x * 256 + threadIdx.x) * 4;
  float4 v = *(const float4*)(x + i);
  uint2 p;
  p.x = pack2bf(v.x, v.y);
  p.y = pack2bf(v.z, v.w);
  *(uint2*)(xb + i) = p;
}

// ---------------- prep: W (k,n) fp32 -> Wt (n,k) bf16 ----------------
__global__ __launch_bounds__(256) void transpose_w_kernel(const float* __restrict__ w0, const float* __restrict__ w1,
                                                          const float* __restrict__ w2, const float* __restrict__ w3,
                                                          u16* __restrict__ dqkv, u16* __restrict__ dwo) {
  __shared__ float t[32][33];
  int z = blockIdx.z;
  const float* src = (z==0) ? w0 : (z==1) ? w1 : (z==2) ? w2 : w3;
  u16* dst = (z < 3) ? (dqkv + (size_t)z * HIDDEN * HIDDEN) : dwo;
  int kb = blockIdx.x * 32, nb = blockIdx.y * 32;
  int tx = threadIdx.x & 31, ty = threadIdx.x >> 5;
  for (int r = ty; r < 32; r += 8) t[r][tx] = src[(size_t)(kb + r) * HIDDEN + nb + tx];
  __syncthreads();
  for (int r = ty; r < 32; r += 8) dst[(size_t)(nb + r) * HIDDEN + kb + tx] = f2bf(t[tx][r]);
}

// ---------------- bf16 GEMM: C[m,n] = sum_k A[m,k]*Bt[n,k] + bias ----------------
// 128x128 tile, BK=32, global_load_lds width-16 staging (m97 structure).
// MODE 0: fp32 out = acc + b0[n]          (output projection)
// MODE 1: fused QKV epilogue: Q seg -> qkvb scaled by CEXP; K seg -> qkvb;
//         V seg -> vtb transposed [bh*64+d][token] (packed b64 stores).
template<int MODE>
__global__ __launch_bounds__(256) void gemm_bt(const u16* __restrict__ A, const u16* __restrict__ Bt,
                                               const float* __restrict__ b0, const float* __restrict__ b1,
                                               const float* __restrict__ b2,
                                               u16* __restrict__ Cq, u16* __restrict__ Vt,
                                               float* __restrict__ Cf, int M, int N, int K) {
  __shared__ u16 As[128*32];
  __shared__ u16 Bs[128*32];
  const int tid = threadIdx.x, lane = tid & 63, wv = tid >> 6;
  const int m0 = blockIdx.x * 128, n0 = blockIdx.y * 128;
  const int wm = (wv >> 1) * 64, wn = (wv & 1) * 64;
  const int col = lane & 15, quad = lane >> 4;
  const int lr = lane >> 2, lk = (lane & 3) * 8;
  f32x4 acc[4][4] = {};
  for (int k0 = 0; k0 < K; k0 += 32) {
    gload16(&A [(size_t)(m0 + wv*32      + lr)*K + k0 + lk], &As[wv*1024]);
    gload16(&A [(size_t)(m0 + wv*32 + 16 + lr)*K + k0 + lk], &As[wv*1024 + 512]);
    gload16(&Bt[(size_t)(n0 + wv*32      + lr)*K + k0 + lk], &Bs[wv*1024]);
    gload16(&Bt[(size_t)(n0 + wv*32 + 16 + lr)*K + k0 + lk], &Bs[wv*1024 + 512]);
    __syncthreads();
    bf16x8 af[4], bfr[4];
    #pragma unroll
    for (int i = 0; i < 4; i++) af[i]  = *(const bf16x8*)&As[(wm + i*16 + col)*32 + quad*8];
    #pragma unroll
    for (int i = 0; i < 4; i++) bfr[i] = *(const bf16x8*)&Bs[(wn + i*16 + col)*32 + quad*8];
    #pragma unroll
    for (int mi = 0; mi < 4; mi++)
      #pragma unroll
      for (int ni = 0; ni < 4; ni++)
        acc[mi][ni] = __builtin_amdgcn_mfma_f32_16x16x32_bf16(af[mi], bfr[ni], acc[mi][ni], 0, 0, 0);
    __syncthreads();
  }
  if constexpr (MODE == 0) {
    #pragma unroll
    for (int mi = 0; mi < 4; mi++)
      #pragma unroll
      for (int ni = 0; ni < 4; ni++) {
        int n = n0 + wn + ni*16 + col;
        float bias = b0[n];
        #pragma unroll
        for (int r = 0; r < 4; r++) {
          int m = m0 + wm + mi*16 + quad*4 + r;   // C/D: row = quad*4+reg, col = lane&15
          Cf[(size_t)m*N + n] = acc[mi][ni][r] + bias;
        }
      }
  } else {
    const int seg = n0 >> 10;   // 0=Q, 1=K, 2=V (n0 is 128-aligned)
    if (seg == 2) {
      // V: store transposed into Vt[(b*16+h)*64 + d][token]
      #pragma unroll
      for (int ni = 0; ni < 4; ni++) {
        int n = n0 + wn + ni*16 + col;
        int d = n & 63, h = (n >> 6) & 15;
        float bias = b2[n & (HIDDEN-1)];
        #pragma unroll
        for (int mi = 0; mi < 4; mi++) {
          int mb = m0 + wm + mi*16 + quad*4;
          int bb = mb >> 11, tok = mb & (SEQ-1);
          uint2 w2;
          w2.x = pack2bf(acc[mi][ni][0] + bias, acc[mi][ni][1] + bias);
          w2.y = pack2bf(acc[mi][ni][2] + bias, acc[mi][ni][3] + bias);
          *(uint2*)&Vt[((size_t)((bb*NH + h)*HD + d))*SEQ + tok] = w2;
        }
      }
    } else {
      const float* bias = (seg == 0) ? b0 : b1;
      const float scl = (seg == 0) ? CEXP : 1.0f;
      #pragma unroll
      for (int mi = 0; mi < 4; mi++)
        #pragma unroll
        for (int ni = 0; ni < 4; ni++) {
          int n = n0 + wn + ni*16 + col;
          float bv = bias[n & (HIDDEN-1)];
          #pragma unroll
          for (int r = 0; r < 4; r++) {
            int m = m0 + wm + mi*16 + quad*4 + r;
            Cq[(size_t)m*N + n] = f2bf((acc[mi][ni][r] + bv) * scl);
          }
        }
    }
  }
}

// ---------------- flash attention, transposed (S^T = K Q^T), no-max softmax ----------------
// block: 128 q of one (b,h); 4 waves x 32 q. Double-buffered K/V LDS, ONE barrier/iter.
// Q pre-scaled by CEXP in GEMM epilogue -> p = exp2(s) directly.
// Row sums via ones-MFMA against P fragments (no scalar adds, no final shuffles).
__global__ __launch_bounds__(256) void attn_kernel(const u16* __restrict__ qkv,
                                                   const u16* __restrict__ vt,
                                                   u16* __restrict__ ao) {
  __shared__ u16 Ks[2*64*72];    // [buf][t][d], stride 72
  __shared__ u16 Vs[2*64*72];    // [buf][d][t]
  __shared__ u16 Ps[4][32*72];   // per-wave P^T [q(32)][t(64)]
  const int tid = threadIdx.x, lane = tid & 63, wv = tid >> 6;
  const int qt = blockIdx.x, bh = blockIdx.y;
  const int b = bh >> 4, h = bh & 15;
  const int col = lane & 15, quad = lane >> 4;

  // Q as B-fragments (n=lane&15, k=quad*8+j): 2 q-subtiles x 2 k-halves
  bf16x8 qf[2][2];
  #pragma unroll
  for (int nq = 0; nq < 2; nq++) {
    const u16* qrow = qkv + (size_t)(b*SEQ + qt*128 + wv*32 + nq*16 + col) * (3*HIDDEN) + h*HD + quad*8;
    qf[nq][0] = *(const bf16x8*)(qrow);
    qf[nq][1] = *(const bf16x8*)(qrow + 32);
  }
  bf16x8 ones;
  #pragma unroll
  for (int i = 0; i < 8; i++) ones[i] = (__bf16)1.0f;

  f32x4 o[2][4] = {};      // O^T acc: [nq][mi], col=q, row=d
  f32x4 rsacc[2] = {};     // row-sum acc via ones-MFMA (all 4 regs equal)

  const int r0 = tid >> 3, r1 = (tid >> 3) + 32, koS = (tid & 7) * 8;
  const u16* gK = qkv + (size_t)b*SEQ*(3*HIDDEN) + HIDDEN + (size_t)h*HD;   // row stride 3072
  const u16* gV = vt + (size_t)bh*HD*SEQ;                                    // row stride 2048
  uint4 pK0 = *(const uint4*)&gK[(size_t)r0*(3*HIDDEN) + koS];
  uint4 pK1 = *(const uint4*)&gK[(size_t)r1*(3*HIDDEN) + koS];
  uint4 pV0 = *(const uint4*)&gV[(size_t)r0*SEQ + koS];
  uint4 pV1 = *(const uint4*)&gV[(size_t)r1*SEQ + koS];

  for (int it = 0; it < SEQ/64; ++it) {
    const int cur = (it & 1) * 4608;
    // write tile it into buf[it&1] (all other waves are past barrier(it-1),
    // at most reading buf[(it-1)&1] -> safe with a single barrier per iter)
    *(uint4*)&Ks[cur + r0*72 + koS] = pK0;
    *(uint4*)&Ks[cur + r1*72 + koS] = pK1;
    *(uint4*)&Vs[cur + r0*72 + koS] = pV0;
    *(uint4*)&Vs[cur + r1*72 + koS] = pV1;
    __syncthreads();   // tile it visible; prior reads of this buf long done
    if (it < SEQ/64 - 1) {   // prefetch after barrier: loads fly during compute
      int t0 = (it + 1) * 64;
      pK0 = *(const uint4*)&gK[(size_t)(t0 + r0)*(3*HIDDEN) + koS];
      pK1 = *(const uint4*)&gK[(size_t)(t0 + r1)*(3*HIDDEN) + koS];
      pV0 = *(const uint4*)&gV[(size_t)r0*SEQ + t0 + koS];
      pV1 = *(const uint4*)&gV[(size_t)r1*SEQ + t0 + koS];
    }

    // S^T = K Q^T: A=K (m=t), B=Q (n=q). s[nq][nt]: lane q=col, t=nt*16+quad*4+r.
    f32x4 s[2][4] = {};
    #pragma unroll
    for (int kk = 0; kk < 2; kk++)
      #pragma unroll
      for (int nt = 0; nt < 4; nt++) {
        bf16x8 kf = *(const bf16x8*)&Ks[cur + (nt*16 + col)*72 + kk*32 + quad*8];
        #pragma unroll
        for (int nq = 0; nq < 2; nq++)
          s[nq][nt] = __builtin_amdgcn_mfma_f32_16x16x32_bf16(kf, qf[nq][kk], s[nq][nt], 0, 0, 0);
      }

    // p = exp2(s) (Q pre-scaled); packed P^T write
    #pragma unroll
    for (int nq = 0; nq < 2; nq++)
      #pragma unroll
      for (int nt = 0; nt < 4; nt++) {
        float p0 = __builtin_exp2f(s[nq][nt][0]);
        float p1 = __builtin_exp2f(s[nq][nt][1]);
        float p2 = __builtin_exp2f(s[nq][nt][2]);
        float p3 = __builtin_exp2f(s[nq][nt][3]);
        uint2 w2; w2.x = pack2bf(p0, p1); w2.y = pack2bf(p2, p3);
        *(uint2*)&Ps[wv][(nq*16 + col)*72 + nt*16 + quad*4] = w2;   // P^T[q][t]
      }
    asm volatile("s_waitcnt lgkmcnt(0)" ::: "memory");  // same-wave write->read ordering

    // O^T += V^T P^T; row sums += ones * P^T
    #pragma unroll
    for (int kk = 0; kk < 2; kk++) {
      bf16x8 pf[2];
      #pragma unroll
      for (int nq = 0; nq < 2; nq++)
        pf[nq] = *(const bf16x8*)&Ps[wv][(nq*16 + col)*72 + kk*32 + quad*8];
      #pragma unroll
      for (int mi = 0; mi < 4; mi++) {
        bf16x8 vf = *(const bf16x8*)&Vs[cur + (mi*16 + col)*72 + kk*32 + quad*8];
        #pragma unroll
        for (int nq = 0; nq < 2; nq++)
          o[nq][mi] = __builtin_amdgcn_mfma_f32_16x16x32_bf16(vf, pf[nq], o[nq][mi], 0, 0, 0);
      }
      #pragma unroll
      for (int nq = 0; nq < 2; nq++)
        rsacc[nq] = __builtin_amdgcn_mfma_f32_16x16x32_bf16(ones, pf[nq], rsacc[nq], 0, 0, 0);
    }
  }

  // normalize and store O^T -> ao[q][h*64+d]; rsacc regs all hold full row sum for q=col
  #pragma unroll
  for (int nq = 0; nq < 2; nq++) {
    float inv = 1.0f / rsacc[nq][0];
    u16* aop = ao + (size_t)(b*SEQ + qt*128 + wv*32 + nq*16 + col)*HIDDEN + h*HD;
    #pragma unroll
    for (int mi = 0; mi < 4; mi++) {
      uint2 w2;
      w2.x = pack2bf(o[nq][mi][0]*inv, o[nq][mi][1]*inv);
      w2.y = pack2bf(o[nq][mi][2]*inv, o[nq][mi][3]*inv);
      *(uint2*)&aop[mi*16 + quad*4] = w2;
    }
  }
}

extern "C" void kernel_launch(void* const* d_in, const int* in_sizes, int n_in,
                              void* d_out, int out_size, void* d_ws, size_t ws_size,
                              hipStream_t stream) {
  const float* x  = (const float*)d_in[0];
  const float* Wq = (const float*)d_in[1];
  const float* bq = (const float*)d_in[2];
  const float* Wk = (const float*)d_in[3];
  const float* bk = (const float*)d_in[4];
  const float* Wv = (const float*)d_in[5];
  const float* bv = (const float*)d_in[6];
  const float* Wo = (const float*)d_in[7];
  const float* bo = (const float*)d_in[8];
  float* out = (float*)d_out;

  char* w = (char*)d_ws;
  u16* xb    = (u16*)w; w += (size_t)MTOT*HIDDEN*2;        // 8 MB
  u16* wtqkv = (u16*)w; w += (size_t)3*HIDDEN*HIDDEN*2;    // 6 MB
  u16* wto   = (u16*)w; w += (size_t)HIDDEN*HIDDEN*2;      // 2 MB
  u16* qkvb  = (u16*)w; w += (size_t)MTOT*3*HIDDEN*2;      // 24 MB
  u16* vtb   = (u16*)w; w += (size_t)BATCH*NH*HD*SEQ*2;    // 8 MB
  u16* aob   = (u16*)w; w += (size_t)MTOT*HIDDEN*2;        // 8 MB

  convert_x_kernel<<<(MTOT*HIDDEN)/1024, 256, 0, stream>>>(x, xb);
  transpose_w_kernel<<<dim3(32, 32, 4), 256, 0, stream>>>(Wq, Wk, Wv, Wo, wtqkv, wto);
  gemm_bt<1><<<dim3(32, 24), 256, 0, stream>>>(xb, wtqkv, bq, bk, bv, qkvb, vtb, nullptr, MTOT, 3*HIDDEN, HIDDEN);
  attn_kernel<<<dim3(SEQ/128, BATCH*NH), 256, 0, stream>>>(qkvb, vtb, aob);
  gemm_bt<0><<<dim3(32, 8), 256, 0, stream>>>(aob, wto, bo, nullptr, nullptr, nullptr, nullptr, out, MTOT, HIDDEN, HIDDEN);
}

// Round 6
// 229.533 us; speedup vs baseline: 1.0519x; 1.0519x over previous
//
#include <hip/hip_runtime.h>
#include <hip/hip_bf16.h>

typedef unsigned short u16;
typedef __bf16 bf16x8 __attribute__((ext_vector_type(8)));
typedef float f32x4 __attribute__((ext_vector_type(4)));

#define HIDDEN 1024
#define NH 16
#define HD 64
#define BATCH 2
#define SEQ 2048
#define MTOT (BATCH*SEQ)   // 4096
#define CEXP 0.18033688f   // 0.125 * log2(e), folded into Q at projection time

__device__ __forceinline__ u16 f2bf(float f) {
  union { float f; unsigned u; } v; v.f = f;
  unsigned u = v.u;
  return (u16)((u + 0x7fffu + ((u >> 16) & 1u)) >> 16);   // RNE
}

__device__ __forceinline__ unsigned pack2bf(float a, float b) {
  __hip_bfloat162 h = __float22bfloat162_rn(make_float2(a, b));
  unsigned u; __builtin_memcpy(&u, &h, 4); return u;
}

__device__ __forceinline__ void gload16(const u16* g, u16* l) {
  __builtin_amdgcn_global_load_lds((const __attribute__((address_space(1))) unsigned int*)g,
                                   (__attribute__((address_space(3))) unsigned int*)l, 16, 0, 0);
}

// ---------------- prep: x fp32 -> bf16 ----------------
__global__ __launch_bounds__(256) void convert_x_kernel(const float* __restrict__ x,
                                                        u16* __restrict__ xb) {
  size_t i = ((size_t)blockIdx.x * 256 + threadIdx.x) * 4;
  float4 v = *(const float4*)(x + i);
  uint2 p;
  p.x = pack2bf(v.x, v.y);
  p.y = pack2bf(v.z, v.w);
  *(uint2*)(xb + i) = p;
}

// ---------------- prep: W (k,n) fp32 -> Wt (n,k) bf16 ----------------
__global__ __launch_bounds__(256) void transpose_w_kernel(const float* __restrict__ w0, const float* __restrict__ w1,
                                                          const float* __restrict__ w2, const float* __restrict__ w3,
                                                          u16* __restrict__ dqkv, u16* __restrict__ dwo) {
  __shared__ float t[32][33];
  int z = blockIdx.z;
  const float* src = (z==0) ? w0 : (z==1) ? w1 : (z==2) ? w2 : w3;
  u16* dst = (z < 3) ? (dqkv + (size_t)z * HIDDEN * HIDDEN) : dwo;
  int kb = blockIdx.x * 32, nb = blockIdx.y * 32;
  int tx = threadIdx.x & 31, ty = threadIdx.x >> 5;
  for (int r = ty; r < 32; r += 8) t[r][tx] = src[(size_t)(kb + r) * HIDDEN + nb + tx];
  __syncthreads();
  for (int r = ty; r < 32; r += 8) dst[(size_t)(nb + r) * HIDDEN + kb + tx] = f2bf(t[tx][r]);
}

// ---------------- prep: V (t,d) -> Vt (d,t) per head ----------------
__global__ __launch_bounds__(256) void transpose_v_kernel(const u16* __restrict__ qkv,
                                                          u16* __restrict__ vt) {
  __shared__ u16 t[32][33];
  int bh = blockIdx.z; int b = bh >> 4, h = bh & 15;
  int t0 = blockIdx.x * 32, d0 = blockIdx.y * 32;
  int tx = threadIdx.x & 31, ty = threadIdx.x >> 5;
  for (int r = ty; r < 32; r += 8)
    t[r][tx] = qkv[(size_t)(b*SEQ + t0 + r) * (3*HIDDEN) + 2*HIDDEN + h*HD + d0 + tx];
  __syncthreads();
  for (int r = ty; r < 32; r += 8)
    vt[(size_t)(bh*HD + d0 + r) * SEQ + t0 + tx] = t[tx][r];
}

// ---------------- bf16 GEMM: C[m,n] = sum_k A[m,k]*Bt[n,k] + bias ----------------
// MT x 128 tile (MT=128 or 64), BK=32, global_load_lds width-16 staging.
// MODE 0: fp32 out = acc + b0[n]                       (output projection)
// MODE 1: bf16 out, 3 segments: Q (scaled by CEXP), K, V -> qkvb
template<int MODE, int MT>
__global__ __launch_bounds__(256) void gemm_bt(const u16* __restrict__ A, const u16* __restrict__ Bt,
                                               const float* __restrict__ b0, const float* __restrict__ b1,
                                               const float* __restrict__ b2,
                                               u16* __restrict__ Cq, float* __restrict__ Cf,
                                               int M, int N, int K) {
  constexpr int MF = MT / 32;           // m-frags per wave: 4 (MT=128) or 2 (MT=64)
  __shared__ u16 As[MT*32];
  __shared__ u16 Bs[128*32];
  const int tid = threadIdx.x, lane = tid & 63, wv = tid >> 6;
  const int m0 = blockIdx.x * MT, n0 = blockIdx.y * 128;
  const int wm = (wv >> 1) * (MT/2), wn = (wv & 1) * 64;
  const int col = lane & 15, quad = lane >> 4;
  const int lr = lane >> 2, lk = (lane & 3) * 8;
  f32x4 acc[MF][4] = {};
  for (int k0 = 0; k0 < K; k0 += 32) {
    if constexpr (MT == 128) {
      gload16(&A[(size_t)(m0 + wv*32      + lr)*K + k0 + lk], &As[wv*1024]);
      gload16(&A[(size_t)(m0 + wv*32 + 16 + lr)*K + k0 + lk], &As[wv*1024 + 512]);
    } else {
      gload16(&A[(size_t)(m0 + wv*16      + lr)*K + k0 + lk], &As[wv*512]);
    }
    gload16(&Bt[(size_t)(n0 + wv*32      + lr)*K + k0 + lk], &Bs[wv*1024]);
    gload16(&Bt[(size_t)(n0 + wv*32 + 16 + lr)*K + k0 + lk], &Bs[wv*1024 + 512]);
    __syncthreads();
    bf16x8 af[MF], bfr[4];
    #pragma unroll
    for (int i = 0; i < MF; i++) af[i]  = *(const bf16x8*)&As[(wm + i*16 + col)*32 + quad*8];
    #pragma unroll
    for (int i = 0; i < 4; i++)  bfr[i] = *(const bf16x8*)&Bs[(wn + i*16 + col)*32 + quad*8];
    #pragma unroll
    for (int mi = 0; mi < MF; mi++)
      #pragma unroll
      for (int ni = 0; ni < 4; ni++)
        acc[mi][ni] = __builtin_amdgcn_mfma_f32_16x16x32_bf16(af[mi], bfr[ni], acc[mi][ni], 0, 0, 0);
    __syncthreads();
  }
  if constexpr (MODE == 0) {
    #pragma unroll
    for (int mi = 0; mi < MF; mi++)
      #pragma unroll
      for (int ni = 0; ni < 4; ni++) {
        int n = n0 + wn + ni*16 + col;
        float bias = b0[n];
        #pragma unroll
        for (int r = 0; r < 4; r++) {
          int m = m0 + wm + mi*16 + quad*4 + r;   // C/D: row = quad*4+reg, col = lane&15
          Cf[(size_t)m*N + n] = acc[mi][ni][r] + bias;
        }
      }
  } else {
    const int seg = n0 >> 10;   // 0=Q, 1=K, 2=V
    const float* bias = (seg == 0) ? b0 : (seg == 1) ? b1 : b2;
    const float scl = (seg == 0) ? CEXP : 1.0f;
    #pragma unroll
    for (int mi = 0; mi < MF; mi++)
      #pragma unroll
      for (int ni = 0; ni < 4; ni++) {
        int n = n0 + wn + ni*16 + col;
        float bv = bias[n & (HIDDEN-1)];
        #pragma unroll
        for (int r = 0; r < 4; r++) {
          int m = m0 + wm + mi*16 + quad*4 + r;
          Cq[(size_t)m*N + n] = f2bf((acc[mi][ni][r] + bv) * scl);
        }
      }
  }
}

// ---------------- flash attention, transposed (S^T = K Q^T), no-max softmax ----------------
// block: 128 q of one (b,h); 4 waves x 32 q. Double-buffered K/V LDS, ONE barrier/iter.
// Q pre-scaled by CEXP -> p = exp2(s). Row sums via ones-MFMA.
// P round-trip relies on same-wave in-order DS pipe (no HW drain; compiler fence only).
__global__ __launch_bounds__(256) void attn_kernel(const u16* __restrict__ qkv,
                                                   const u16* __restrict__ vt,
                                                   u16* __restrict__ ao) {
  __shared__ u16 Ks[2*64*72];    // [buf][t][d], stride 72
  __shared__ u16 Vs[2*64*72];    // [buf][d][t]
  __shared__ u16 Ps[4][32*72];   // per-wave P^T [q(32)][t(64)]
  const int tid = threadIdx.x, lane = tid & 63, wv = tid >> 6;
  const int qt = blockIdx.x, bh = blockIdx.y;
  const int b = bh >> 4, h = bh & 15;
  const int col = lane & 15, quad = lane >> 4;

  // Q as B-fragments (n=lane&15, k=quad*8+j): 2 q-subtiles x 2 k-halves
  bf16x8 qf[2][2];
  #pragma unroll
  for (int nq = 0; nq < 2; nq++) {
    const u16* qrow = qkv + (size_t)(b*SEQ + qt*128 + wv*32 + nq*16 + col) * (3*HIDDEN) + h*HD + quad*8;
    qf[nq][0] = *(const bf16x8*)(qrow);
    qf[nq][1] = *(const bf16x8*)(qrow + 32);
  }
  bf16x8 ones;
  #pragma unroll
  for (int i = 0; i < 8; i++) ones[i] = (__bf16)1.0f;

  f32x4 o[2][4] = {};      // O^T acc: [nq][mi], col=q, row=d
  f32x4 rsacc[2] = {};     // row-sum acc via ones-MFMA

  const int r0 = tid >> 3, r1 = (tid >> 3) + 32, koS = (tid & 7) * 8;
  const u16* gK = qkv + (size_t)b*SEQ*(3*HIDDEN) + HIDDEN + (size_t)h*HD;   // row stride 3072
  const u16* gV = vt + (size_t)bh*HD*SEQ;                                    // row stride 2048
  uint4 pK0 = *(const uint4*)&gK[(size_t)r0*(3*HIDDEN) + koS];
  uint4 pK1 = *(const uint4*)&gK[(size_t)r1*(3*HIDDEN) + koS];
  uint4 pV0 = *(const uint4*)&gV[(size_t)r0*SEQ + koS];
  uint4 pV1 = *(const uint4*)&gV[(size_t)r1*SEQ + koS];

  for (int it = 0; it < SEQ/64; ++it) {
    const int cur = (it & 1) * 4608;
    *(uint4*)&Ks[cur + r0*72 + koS] = pK0;
    *(uint4*)&Ks[cur + r1*72 + koS] = pK1;
    *(uint4*)&Vs[cur + r0*72 + koS] = pV0;
    *(uint4*)&Vs[cur + r1*72 + koS] = pV1;
    __syncthreads();   // tile it visible; other waves at most read the other buffer
    if (it < SEQ/64 - 1) {   // prefetch after barrier: loads fly during compute
      int t0 = (it + 1) * 64;
      pK0 = *(const uint4*)&gK[(size_t)(t0 + r0)*(3*HIDDEN) + koS];
      pK1 = *(const uint4*)&gK[(size_t)(t0 + r1)*(3*HIDDEN) + koS];
      pV0 = *(const uint4*)&gV[(size_t)r0*SEQ + t0 + koS];
      pV1 = *(const uint4*)&gV[(size_t)r1*SEQ + t0 + koS];
    }

    // S^T = K Q^T: A=K (m=t), B=Q (n=q). s[nq][nt]: lane q=col, t=nt*16+quad*4+r.
    f32x4 s[2][4] = {};
    #pragma unroll
    for (int kk = 0; kk < 2; kk++)
      #pragma unroll
      for (int nt = 0; nt < 4; nt++) {
        bf16x8 kf = *(const bf16x8*)&Ks[cur + (nt*16 + col)*72 + kk*32 + quad*8];
        #pragma unroll
        for (int nq = 0; nq < 2; nq++)
          s[nq][nt] = __builtin_amdgcn_mfma_f32_16x16x32_bf16(kf, qf[nq][kk], s[nq][nt], 0, 0, 0);
      }

    // p = exp2(s) (Q pre-scaled); packed P^T write
    #pragma unroll
    for (int nq = 0; nq < 2; nq++)
      #pragma unroll
      for (int nt = 0; nt < 4; nt++) {
        float p0 = __builtin_exp2f(s[nq][nt][0]);
        float p1 = __builtin_exp2f(s[nq][nt][1]);
        float p2 = __builtin_exp2f(s[nq][nt][2]);
        float p3 = __builtin_exp2f(s[nq][nt][3]);
        uint2 w2; w2.x = pack2bf(p0, p1); w2.y = pack2bf(p2, p3);
        *(uint2*)&Ps[wv][(nq*16 + col)*72 + nt*16 + quad*4] = w2;   // P^T[q][t]
      }
    // same-wave DS ops are processed in order by the LDS pipe: no HW drain needed.
    asm volatile("" ::: "memory");   // compiler fence: keep write->read program order

    // O^T += V^T P^T; row sums += ones * P^T
    #pragma unroll
    for (int kk = 0; kk < 2; kk++) {
      bf16x8 pf[2];
      #pragma unroll
      for (int nq = 0; nq < 2; nq++)
        pf[nq] = *(const bf16x8*)&Ps[wv][(nq*16 + col)*72 + kk*32 + quad*8];
      #pragma unroll
      for (int mi = 0; mi < 4; mi++) {
        bf16x8 vf = *(const bf16x8*)&Vs[cur + (mi*16 + col)*72 + kk*32 + quad*8];
        #pragma unroll
        for (int nq = 0; nq < 2; nq++)
          o[nq][mi] = __builtin_amdgcn_mfma_f32_16x16x32_bf16(vf, pf[nq], o[nq][mi], 0, 0, 0);
      }
      #pragma unroll
      for (int nq = 0; nq < 2; nq++)
        rsacc[nq] = __builtin_amdgcn_mfma_f32_16x16x32_bf16(ones, pf[nq], rsacc[nq], 0, 0, 0);
    }
  }

  // normalize and store O^T -> ao[q][h*64+d]
  #pragma unroll
  for (int nq = 0; nq < 2; nq++) {
    float inv = 1.0f / rsacc[nq][0];
    u16* aop = ao + (size_t)(b*SEQ + qt*128 + wv*32 + nq*16 + col)*HIDDEN + h*HD;
    #pragma unroll
    for (int mi = 0; mi < 4; mi++) {
      uint2 w2;
      w2.x = pack2bf(o[nq][mi][0]*inv, o[nq][mi][1]*inv);
      w2.y = pack2bf(o[nq][mi][2]*inv, o[nq][mi][3]*inv);
      *(uint2*)&aop[mi*16 + quad*4] = w2;
    }
  }
}

extern "C" void kernel_launch(void* const* d_in, const int* in_sizes, int n_in,
                              void* d_out, int out_size, void* d_ws, size_t ws_size,
                              hipStream_t stream) {
  const float* x  = (const float*)d_in[0];
  const float* Wq = (const float*)d_in[1];
  const float* bq = (const float*)d_in[2];
  const float* Wk = (const float*)d_in[3];
  const float* bk = (const float*)d_in[4];
  const float* Wv = (const float*)d_in[5];
  const float* bv = (const float*)d_in[6];
  const float* Wo = (const float*)d_in[7];
  const float* bo = (const float*)d_in[8];
  float* out = (float*)d_out;

  char* w = (char*)d_ws;
  u16* xb    = (u16*)w; w += (size_t)MTOT*HIDDEN*2;        // 8 MB
  u16* wtqkv = (u16*)w; w += (size_t)3*HIDDEN*HIDDEN*2;    // 6 MB
  u16* wto   = (u16*)w; w += (size_t)HIDDEN*HIDDEN*2;      // 2 MB
  u16* qkvb  = (u16*)w; w += (size_t)MTOT*3*HIDDEN*2;      // 24 MB
  u16* vtb   = (u16*)w; w += (size_t)BATCH*NH*HD*SEQ*2;    // 8 MB
  u16* aob   = (u16*)w; w += (size_t)MTOT*HIDDEN*2;        // 8 MB

  convert_x_kernel<<<(MTOT*HIDDEN)/1024, 256, 0, stream>>>(x, xb);
  transpose_w_kernel<<<dim3(32, 32, 4), 256, 0, stream>>>(Wq, Wk, Wv, Wo, wtqkv, wto);
  gemm_bt<1,128><<<dim3(32, 24), 256, 0, stream>>>(xb, wtqkv, bq, bk, bv, qkvb, nullptr, MTOT, 3*HIDDEN, HIDDEN);
  transpose_v_kernel<<<dim3(SEQ/32, 2, BATCH*NH), 256, 0, stream>>>(qkvb, vtb);
  attn_kernel<<<dim3(SEQ/128, BATCH*NH), 256, 0, stream>>>(qkvb, vtb, aob);
  gemm_bt<0,64><<<dim3(64, 8), 256, 0, stream>>>(aob, wto, bo, nullptr, nullptr, nullptr, out, MTOT, HIDDEN, HIDDEN);
}